// Round 3
// baseline (154.685 us; speedup 1.0000x reference)
//
#include <hip/hip_runtime.h>

namespace {

constexpr int Dh   = 64;
constexpr int Sseq = 2048;
constexpr int NT   = Sseq / 64;     // 32 q-tiles per head
constexpr int BH   = 32;            // B*H
constexpr float SCALE = 0.125f;     // 1/sqrt(64), folded into K pre-pass
constexpr float DEFER_THR = 8.0f;   // T13 defer-max threshold (nats)

typedef __attribute__((ext_vector_type(8))) short frag8;      // 8 bf16 MFMA operand
typedef __attribute__((ext_vector_type(4))) float f32x4;      // MFMA accumulator
typedef __attribute__((ext_vector_type(4))) short short4v;
typedef __attribute__((ext_vector_type(4))) unsigned int u32x4;

__device__ __forceinline__ short f2bf(float f) {
    unsigned u = __builtin_bit_cast(unsigned, f);
    u += 0x7FFFu + ((u >> 16) & 1u);          // RNE to bf16
    return (short)(u >> 16);
}
__device__ __forceinline__ unsigned pack2(float lo, float hi) {
    return (unsigned)(unsigned short)f2bf(lo) | ((unsigned)(unsigned short)f2bf(hi) << 16);
}
// key k -> LDS row. [k5][k4k3][k2][k1k0] -> [k5][k2][k4k3][k1k0]: QK-tile t reads
// natural rows t*16+c and S^T lands exactly in the PV A-frag key order.
__device__ __forceinline__ int kperm(int kk) {
    return (kk & 0x23) | ((kk & 4) << 2) | ((kk & 0x18) >> 1);
}

#define GLOAD_LDS16(gsrc, ldst)                                          \
    __builtin_amdgcn_global_load_lds(                                    \
        (const __attribute__((address_space(1))) void*)(gsrc),           \
        (__attribute__((address_space(3))) void*)(ldst), 16, 0, 0)

// ============================================================================
// Pre-pass: fp32 K,V -> bf16 LDS-image layout in d_ws.
// Kp[bh][blk]: row kperm(key), col d ^ ((row&7)<<3), K scaled by 1/sqrt(D).
// Vp[bh][blk]: row d,          col key ^ ((d&7)<<3)   (V transposed).
// ============================================================================
__global__ __launch_bounds__(256) void prep_kernel(
    const float* __restrict__ kg, const float* __restrict__ vg,
    short* __restrict__ kp, short* __restrict__ vp)
{
    const int n   = blockIdx.x;            // 0..1023 = bh*32 + blk
    const int blk = n & 31;
    const float* ksrc = kg + ((size_t)(n >> 5) * Sseq + blk * 64) * Dh;
    const float* vsrc = vg + ((size_t)(n >> 5) * Sseq + blk * 64) * Dh;
    short* kdst = kp + (size_t)n * 4096;
    short* vdst = vp + (size_t)n * 4096;
    const int tid = threadIdx.x;

    #pragma unroll
    for (int p = 0; p < 4; ++p) {
        const int fe = (tid + p * 256) * 4;
        const float4 x = *(const float4*)(ksrc + fe);
        const int key = fe >> 6, d0 = fe & 63;
        const int srow = kperm(key);
        const int scol = d0 ^ ((srow & 7) << 3);
        short4v y;
        y[0] = f2bf(x.x * SCALE); y[1] = f2bf(x.y * SCALE);
        y[2] = f2bf(x.z * SCALE); y[3] = f2bf(x.w * SCALE);
        *(short4v*)&kdst[srow * 64 + scol] = y;
    }
    const int vd = tid & 63, vkq = tid >> 6;
    const int vswz = (vd & 7) << 3;
    const float* vcol = vsrc + vkq * 16 * Dh + vd;
    frag8 y0, y1;
    #pragma unroll
    for (int i = 0; i < 8; ++i) { y0[i] = f2bf(vcol[i * Dh]); y1[i] = f2bf(vcol[(i + 8) * Dh]); }
    *(frag8*)&vdst[vd * 64 + ((vkq * 16) ^ vswz)]     = y0;
    *(frag8*)&vdst[vd * 64 + ((vkq * 16 + 8) ^ vswz)] = y1;
}

// ============================================================================
// Main kernel: block-causal flash attention, KV staged via global_load_lds.
// ============================================================================
__global__ __launch_bounds__(256) void battn_kernel(
    const float* __restrict__ qg, const short* __restrict__ kp,
    const short* __restrict__ vp, float* __restrict__ og)
{
    __shared__ short Klds[2][4096];
    __shared__ short Vlds[2][4096];

    const int n   = blockIdx.x;
    const int xcd = n & 7;                 // XCD swizzle: 4 heads per XCD
    const int idx = n >> 3;
    const int bh  = xcd * 4 + (idx >> 4);  // 0..31
    const int qt0 = idx & 15;
    const int qtA = qt0;                   // small tile
    const int qtB = NT - 1 - qt0;          // large tile; 33 tile-steps/WG, balanced
    const int nb  = qtB + 1;

    const float* qh = qg + (size_t)bh * Sseq * Dh;
    float*       oh = og + (size_t)bh * Sseq * Dh;
    const short* kbase = kp + (size_t)bh * 32 * 4096;
    const short* vbase = vp + (size_t)bh * 32 * 4096;

    const int tid  = threadIdx.x;
    const int lane = tid & 63;
    const int w    = tid >> 6;     // wave 0..3 owns q-rows [w*16, w*16+16) of BOTH tiles
    const int g    = lane >> 4;
    const int c    = lane & 15;    // this lane's q-row within the wave
    const int swzc = (c & 7) << 3; // read-side XOR swizzle (short units)

    // ---- Q fragments, both tiles (QK B-operand: lane holds Q[qrow=c][d=ks*32+g*8+j]) ----
    frag8 qfA[2], qfB[2];
    {
        const float* qrA = qh + (size_t)(qtA * 64 + w * 16 + c) * Dh;
        const float* qrB = qh + (size_t)(qtB * 64 + w * 16 + c) * Dh;
        #pragma unroll
        for (int ks = 0; ks < 2; ++ks) {
            const float4 a0 = *(const float4*)(qrA + ks * 32 + g * 8);
            const float4 a1 = *(const float4*)(qrA + ks * 32 + g * 8 + 4);
            const float4 b0 = *(const float4*)(qrB + ks * 32 + g * 8);
            const float4 b1 = *(const float4*)(qrB + ks * 32 + g * 8 + 4);
            qfA[ks][0] = f2bf(a0.x); qfA[ks][1] = f2bf(a0.y);
            qfA[ks][2] = f2bf(a0.z); qfA[ks][3] = f2bf(a0.w);
            qfA[ks][4] = f2bf(a1.x); qfA[ks][5] = f2bf(a1.y);
            qfA[ks][6] = f2bf(a1.z); qfA[ks][7] = f2bf(a1.w);
            qfB[ks][0] = f2bf(b0.x); qfB[ks][1] = f2bf(b0.y);
            qfB[ks][2] = f2bf(b0.z); qfB[ks][3] = f2bf(b0.w);
            qfB[ks][4] = f2bf(b1.x); qfB[ks][5] = f2bf(b1.y);
            qfB[ks][6] = f2bf(b1.z); qfB[ks][7] = f2bf(b1.w);
        }
    }

    // wave w stages 2KB of K and 2KB of V per block (linear dest, pre-swizzled src)
    auto issue_gload = [&](int blk, int buf) {
        const short* ks = kbase + blk * 4096 + w * 1024 + lane * 8;
        const short* vs = vbase + blk * 4096 + w * 1024 + lane * 8;
        GLOAD_LDS16(ks,       &Klds[buf][w * 1024]);
        GLOAD_LDS16(ks + 512, &Klds[buf][w * 1024 + 512]);
        GLOAD_LDS16(vs,       &Vlds[buf][w * 1024]);
        GLOAD_LDS16(vs + 512, &Vlds[buf][w * 1024 + 512]);
    };

    float mA = -1e30f, lA = 0.f, mB = -1e30f, lB = 0.f;
    f32x4 oA[4], oB[4];
    #pragma unroll
    for (int t = 0; t < 4; ++t) { oA[t] = f32x4{0,0,0,0}; oB[t] = f32x4{0,0,0,0}; }

    // online softmax for one tile; emits packed bf16 P in PV A-frag order
    auto softmax = [&](const f32x4* s, float& m_run, float& l_run, f32x4* oacc, u32x4* paf) {
        float pmax = s[0][0];
        #pragma unroll
        for (int t = 0; t < 4; ++t)
            #pragma unroll
            for (int r = 0; r < 4; ++r) pmax = fmaxf(pmax, s[t][r]);
        pmax = fmaxf(pmax, __shfl_xor(pmax, 16));
        pmax = fmaxf(pmax, __shfl_xor(pmax, 32));
        if (!__all(pmax <= m_run + DEFER_THR)) {     // T13 defer-max
            const float mn   = fmaxf(m_run, pmax);
            const float corr = __expf(m_run - mn);
            m_run = mn;
            l_run *= corr;
            #pragma unroll
            for (int r = 0; r < 4; ++r) {
                const float cr = __shfl(corr, g * 4 + r);   // O rows are g*4+r
                #pragma unroll
                for (int t = 0; t < 4; ++t) oacc[t][r] *= cr;
            }
        }
        float e[4][4];
        float rs = 0.f;
        #pragma unroll
        for (int t = 0; t < 4; ++t)
            #pragma unroll
            for (int r = 0; r < 4; ++r) { e[t][r] = __expf(s[t][r] - m_run); rs += e[t][r]; }
        rs += __shfl_xor(rs, 16);
        rs += __shfl_xor(rs, 32);
        l_run += rs;
        paf[0] = u32x4{pack2(e[0][0], e[0][1]), pack2(e[0][2], e[0][3]),
                       pack2(e[1][0], e[1][1]), pack2(e[1][2], e[1][3])};
        paf[1] = u32x4{pack2(e[2][0], e[2][1]), pack2(e[2][2], e[2][3]),
                       pack2(e[3][0], e[3][1]), pack2(e[3][2], e[3][3])};
    };

    issue_gload(0, 0);
    int cur = 0;
    for (int sb = 0; sb < nb; ++sb) {
        __syncthreads();                       // drains vmcnt(0): buf[cur] ready for all
        if (sb + 1 < nb) issue_gload(sb + 1, cur ^ 1);   // in flight across compute
        const bool doA = (sb <= qtA);          // wave-uniform

        // ---- S^T = K·Q^T, dual-tile: each kf read feeds both tiles ----
        f32x4 sB[4], sA[4];
        #pragma unroll
        for (int t = 0; t < 4; ++t) {
            f32x4 aB = f32x4{0,0,0,0}, aA = f32x4{0,0,0,0};
            #pragma unroll
            for (int ks = 0; ks < 2; ++ks) {
                const frag8 kf = *(const frag8*)&Klds[cur][(t * 16 + c) * 64 + ((ks * 32 + g * 8) ^ swzc)];
                aB = __builtin_amdgcn_mfma_f32_16x16x32_bf16(kf, qfB[ks], aB, 0, 0, 0);
                if (doA) aA = __builtin_amdgcn_mfma_f32_16x16x32_bf16(kf, qfA[ks], aA, 0, 0, 0);
            }
            sB[t] = aB; sA[t] = aA;
        }

        u32x4 pafB[2], pafA[2];
        softmax(sB, mB, lB, oB, pafB);
        if (doA) softmax(sA, mA, lA, oA, pafA);

        // ---- O += P·V, dual-tile: each vf read feeds both tiles ----
        #pragma unroll
        for (int ks = 0; ks < 2; ++ks) {
            const frag8 pB = __builtin_bit_cast(frag8, pafB[ks]);
            const frag8 pA = __builtin_bit_cast(frag8, pafA[ks]);
            #pragma unroll
            for (int t = 0; t < 4; ++t) {
                const frag8 vf = *(const frag8*)&Vlds[cur][(t * 16 + c) * 64 + ((ks * 32 + g * 8) ^ swzc)];
                oB[t] = __builtin_amdgcn_mfma_f32_16x16x32_bf16(pB, vf, oB[t], 0, 0, 0);
                if (doA) oA[t] = __builtin_amdgcn_mfma_f32_16x16x32_bf16(pA, vf, oA[t], 0, 0, 0);
            }
        }
        cur ^= 1;
    }

    auto store_tile = [&](int qt, float l_run, const f32x4* oacc) {
        const float linv = 1.f / l_run;
        #pragma unroll
        for (int r = 0; r < 4; ++r) {
            const float lr = __shfl(linv, g * 4 + r);
            float* orow = oh + (size_t)(qt * 64 + w * 16 + g * 4 + r) * Dh;
            #pragma unroll
            for (int t = 0; t < 4; ++t) orow[t * 16 + c] = oacc[t][r] * lr;
        }
    };
    store_tile(qtB, lB, oB);
    store_tile(qtA, lA, oA);
}

// ============================================================================
// Fallback (round-2 kernel, self-converting) for the case ws_size is too small.
// ============================================================================
__global__ __launch_bounds__(256) void battn_fb(
    const float* __restrict__ qg, const float* __restrict__ kg,
    const float* __restrict__ vg, float* __restrict__ og)
{
    __shared__ short Klds[2][64 * 64];
    __shared__ short Vlds[2][64 * 64];

    const int n   = blockIdx.x;
    const int xcd = n & 7;
    const int idx = n >> 3;
    const int bh  = xcd * 4 + (idx >> 4);
    const int qt0 = idx & 15;
    const int qtA = qt0;
    const int qtB = NT - 1 - qt0;
    const int nb  = qtB + 1;

    const size_t hoff = (size_t)bh * Sseq * Dh;
    const float* qh = qg + hoff;
    const float* kh = kg + hoff;
    const float* vh = vg + hoff;
    float*       oh = og + hoff;

    const int tid  = threadIdx.x;
    const int lane = tid & 63;
    const int w    = tid >> 6;
    const int g    = lane >> 4;
    const int c    = lane & 15;
    const int swzc = (c & 7) << 3;
    const int vd   = tid & 63;
    const int vkq  = tid >> 6;
    const int vswz = (vd & 7) << 3;

    frag8 qfA[2], qfB[2];
    {
        const float* qrA = qh + (size_t)(qtA * 64 + w * 16 + c) * Dh;
        const float* qrB = qh + (size_t)(qtB * 64 + w * 16 + c) * Dh;
        #pragma unroll
        for (int ks = 0; ks < 2; ++ks) {
            const float4 a0 = *(const float4*)(qrA + ks * 32 + g * 8);
            const float4 a1 = *(const float4*)(qrA + ks * 32 + g * 8 + 4);
            const float4 b0 = *(const float4*)(qrB + ks * 32 + g * 8);
            const float4 b1 = *(const float4*)(qrB + ks * 32 + g * 8 + 4);
            qfA[ks][0] = f2bf(a0.x * SCALE); qfA[ks][1] = f2bf(a0.y * SCALE);
            qfA[ks][2] = f2bf(a0.z * SCALE); qfA[ks][3] = f2bf(a0.w * SCALE);
            qfA[ks][4] = f2bf(a1.x * SCALE); qfA[ks][5] = f2bf(a1.y * SCALE);
            qfA[ks][6] = f2bf(a1.z * SCALE); qfA[ks][7] = f2bf(a1.w * SCALE);
            qfB[ks][0] = f2bf(b0.x * SCALE); qfB[ks][1] = f2bf(b0.y * SCALE);
            qfB[ks][2] = f2bf(b0.z * SCALE); qfB[ks][3] = f2bf(b0.w * SCALE);
            qfB[ks][4] = f2bf(b1.x * SCALE); qfB[ks][5] = f2bf(b1.y * SCALE);
            qfB[ks][6] = f2bf(b1.z * SCALE); qfB[ks][7] = f2bf(b1.w * SCALE);
        }
    }

    float4 kx[4];
    float  vx[16];
    auto issue_loads = [&](int blk) {
        const float4* ksrc = (const float4*)(kh + (size_t)blk * 64 * Dh);
        #pragma unroll
        for (int p = 0; p < 4; ++p) kx[p] = ksrc[tid + p * 256];
        const float* vsrc = vh + ((size_t)blk * 64 + vkq * 16) * Dh + vd;
        #pragma unroll
        for (int i = 0; i < 16; ++i) vx[i] = vsrc[i * Dh];
    };
    auto write_stage = [&](int buf) {
        #pragma unroll
        for (int p = 0; p < 4; ++p) {
            const int fe   = (tid + p * 256) * 4;
            const int key  = fe >> 6;
            const int srow = kperm(key);
            const int scol = (fe & 63) ^ ((srow & 7) << 3);
            short4v y;
            y[0] = f2bf(kx[p].x); y[1] = f2bf(kx[p].y);
            y[2] = f2bf(kx[p].z); y[3] = f2bf(kx[p].w);
            *(short4v*)&Klds[buf][srow * 64 + scol] = y;
        }
        frag8 y0, y1;
        #pragma unroll
        for (int i = 0; i < 8; ++i) { y0[i] = f2bf(vx[i]); y1[i] = f2bf(vx[8 + i]); }
        *(frag8*)&Vlds[buf][vd * 64 + ((vkq * 16) ^ vswz)]     = y0;
        *(frag8*)&Vlds[buf][vd * 64 + ((vkq * 16 + 8) ^ vswz)] = y1;
    };

    float mA = -1e30f, lA = 0.f, mB = -1e30f, lB = 0.f;
    f32x4 oA[4], oB[4];
    #pragma unroll
    for (int t = 0; t < 4; ++t) { oA[t] = f32x4{0,0,0,0}; oB[t] = f32x4{0,0,0,0}; }

    auto tile_step = [&](int buf, const frag8* qf, float& m_run, float& l_run, f32x4* oacc) {
        f32x4 s[4];
        #pragma unroll
        for (int t = 0; t < 4; ++t) {
            f32x4 acc = f32x4{0, 0, 0, 0};
            #pragma unroll
            for (int ks = 0; ks < 2; ++ks) {
                const frag8 kf = *(const frag8*)&Klds[buf][(t * 16 + c) * 64 + ((ks * 32 + g * 8) ^ swzc)];
                acc = __builtin_amdgcn_mfma_f32_16x16x32_bf16(kf, qf[ks], acc, 0, 0, 0);
            }
            s[t] = acc;
        }
        float pmax = s[0][0];
        #pragma unroll
        for (int t = 0; t < 4; ++t)
            #pragma unroll
            for (int r = 0; r < 4; ++r) pmax = fmaxf(pmax, s[t][r]);
        pmax = fmaxf(pmax, __shfl_xor(pmax, 16));
        pmax = fmaxf(pmax, __shfl_xor(pmax, 32));
        if (!__all(pmax <= m_run + DEFER_THR)) {
            const float mn   = fmaxf(m_run, pmax);
            const float corr = __expf(m_run - mn);
            m_run = mn;
            l_run *= corr;
            #pragma unroll
            for (int r = 0; r < 4; ++r) {
                const float cr = __shfl(corr, g * 4 + r);
                #pragma unroll
                for (int t = 0; t < 4; ++t) oacc[t][r] *= cr;
            }
        }
        float e[4][4];
        float rs = 0.f;
        #pragma unroll
        for (int t = 0; t < 4; ++t)
            #pragma unroll
            for (int r = 0; r < 4; ++r) { e[t][r] = __expf(s[t][r] - m_run); rs += e[t][r]; }
        rs += __shfl_xor(rs, 16);
        rs += __shfl_xor(rs, 32);
        l_run += rs;
        u32x4 paf[2];
        paf[0] = u32x4{pack2(e[0][0], e[0][1]), pack2(e[0][2], e[0][3]),
                       pack2(e[1][0], e[1][1]), pack2(e[1][2], e[1][3])};
        paf[1] = u32x4{pack2(e[2][0], e[2][1]), pack2(e[2][2], e[2][3]),
                       pack2(e[3][0], e[3][1]), pack2(e[3][2], e[3][3])};
        #pragma unroll
        for (int ks = 0; ks < 2; ++ks) {
            const frag8 pf = __builtin_bit_cast(frag8, paf[ks]);
            #pragma unroll
            for (int t = 0; t < 4; ++t) {
                const frag8 vf = *(const frag8*)&Vlds[buf][(t * 16 + c) * 64 + ((ks * 32 + g * 8) ^ swzc)];
                oacc[t] = __builtin_amdgcn_mfma_f32_16x16x32_bf16(pf, vf, oacc[t], 0, 0, 0);
            }
        }
    };

    issue_loads(0);
    write_stage(0);
    int cur = 0;
    for (int sb = 0; sb < nb; ++sb) {
        const bool haveNext = (sb + 1 < nb);
        __syncthreads();
        if (haveNext) issue_loads(sb + 1);
        tile_step(cur, qfB, mB, lB, oB);
        if (sb <= qtA) tile_step(cur, qfA, mA, lA, oA);
        if (haveNext) write_stage(cur ^ 1);
        cur ^= 1;
    }

    auto store_tile = [&](int qt, float l_run, const f32x4* oacc) {
        const float linv = 1.f / l_run;
        #pragma unroll
        for (int r = 0; r < 4; ++r) {
            const float lr = __shfl(linv, g * 4 + r);
            float* orow = oh + (size_t)(qt * 64 + w * 16 + g * 4 + r) * Dh;
            #pragma unroll
            for (int t = 0; t < 4; ++t) orow[t * 16 + c] = oacc[t][r] * lr;
        }
    };
    store_tile(qtB, lB, oB);
    store_tile(qtA, lA, oA);
}

} // namespace

extern "C" void kernel_launch(void* const* d_in, const int* in_sizes, int n_in,
                              void* d_out, int out_size, void* d_ws, size_t ws_size,
                              hipStream_t stream) {
    const float* q = (const float*)d_in[0];
    const float* k = (const float*)d_in[1];
    const float* v = (const float*)d_in[2];
    float* out = (float*)d_out;

    const size_t tensor_shorts = (size_t)BH * 32 * 4096;        // 4096 shorts per (bh,blk)
    const size_t need = 2 * tensor_shorts * sizeof(short);      // ~16.8 MB

    if (ws_size >= need) {
        short* kp = (short*)d_ws;
        short* vp = kp + tensor_shorts;
        prep_kernel<<<dim3(BH * 32), dim3(256), 0, stream>>>(k, v, kp, vp);
        battn_kernel<<<dim3(BH * 16), dim3(256), 0, stream>>>(q, kp, vp, out);
    } else {
        battn_fb<<<dim3(BH * 16), dim3(256), 0, stream>>>(q, k, v, out);
    }
}

// Round 4
// 133.608 us; speedup vs baseline: 1.1578x; 1.1578x over previous
//
#include <hip/hip_runtime.h>

namespace {

constexpr int Dh   = 64;
constexpr int Sseq = 2048;
constexpr int NT   = Sseq / 64;     // 32 q-tiles per head
// exp2-domain softmax: fold 1/sqrt(D) * log2(e) into Q once.
constexpr float QSCALE = 0.125f * 1.44269504088896340736f;
constexpr float DEFER_THR = 11.5416f;   // 8 nats in log2 units (T13)

typedef __attribute__((ext_vector_type(8))) short frag8;      // 8 bf16 MFMA operand
typedef __attribute__((ext_vector_type(4))) float f32x4;      // MFMA accumulator
typedef __attribute__((ext_vector_type(4))) short short4v;
typedef __attribute__((ext_vector_type(4))) unsigned int u32x4;

__device__ __forceinline__ short f2bf(float f) {
    unsigned u = __builtin_bit_cast(unsigned, f);
    u += 0x7FFFu + ((u >> 16) & 1u);          // RNE to bf16
    return (short)(u >> 16);
}
__device__ __forceinline__ unsigned pack2(float lo, float hi) {
    return (unsigned)(unsigned short)f2bf(lo) | ((unsigned)(unsigned short)f2bf(hi) << 16);
}
// key k -> LDS row. [k5][k4k3][k2][k1k0] -> [k5][k2][k4k3][k1k0]: QK-tile t reads
// natural rows t*16+c and S^T lands exactly in the PV A-frag key order.
__device__ __forceinline__ int kperm(int kk) {
    return (kk & 0x23) | ((kk & 4) << 2) | ((kk & 0x18) >> 1);
}

__global__ __launch_bounds__(256, 4) void battn_kernel(
    const float* __restrict__ qg, const float* __restrict__ kg,
    const float* __restrict__ vg, float* __restrict__ og)
{
    __shared__ short Klds[2][4096];
    __shared__ short Vlds[2][4096];

    // 1024 WGs. XCD-local heads (4 per XCD) + per-CU qt scrambling for balance:
    // CU slot (xcd, s) gets one WG per layer l with qt = l*8 + ((s>>2)+l)%8.
    const int n   = blockIdx.x;
    const int l   = n >> 8;                    // resident layer 0..3
    const int m   = n & 255;
    const int xcd = m & 7;
    const int s   = m >> 3;                    // 0..31
    const int bh  = xcd * 4 + (s & 3);         // 4 heads per XCD
    const int qt  = (l << 3) | (((s >> 2) + l) & 7);
    const int nb  = qt + 1;                    // visible KV blocks

    const size_t hoff = (size_t)bh * Sseq * Dh;
    const float* qh = qg + hoff;
    const float* kh = kg + hoff;
    const float* vh = vg + hoff;
    float*       oh = og + hoff;

    const int tid  = threadIdx.x;
    const int lane = tid & 63;
    const int w    = tid >> 6;     // wave 0..3 owns q-rows [w*16, w*16+16)
    const int g    = lane >> 4;
    const int c    = lane & 15;    // this lane's q-row within the wave
    const int swzc = (c & 7) << 3; // read-side XOR swizzle (short units)

    const int vd   = tid & 63;     // V^T staging: d
    const int vkq  = tid >> 6;     // V^T staging: key quarter
    const int vswz = (vd & 7) << 3;

    // ---- hoisted LDS fragment offsets (loop-invariant; shared by K and V reads) ----
    int loff[4][2];
    #pragma unroll
    for (int t = 0; t < 4; ++t)
        #pragma unroll
        for (int ks = 0; ks < 2; ++ks)
            loff[t][ks] = (t * 16 + c) * 64 + ((ks * 32 + g * 8) ^ swzc);

    // ---- Q fragment (QK B-operand: lane holds Q[qrow=c][d=ks*32+g*8+j]), exp2-scaled ----
    frag8 qf[2];
    {
        const float* qr = qh + (size_t)(qt * 64 + w * 16 + c) * Dh;
        #pragma unroll
        for (int ks = 0; ks < 2; ++ks) {
            const float4 x0 = *(const float4*)(qr + ks * 32 + g * 8);
            const float4 x1 = *(const float4*)(qr + ks * 32 + g * 8 + 4);
            qf[ks][0] = f2bf(x0.x * QSCALE); qf[ks][1] = f2bf(x0.y * QSCALE);
            qf[ks][2] = f2bf(x0.z * QSCALE); qf[ks][3] = f2bf(x0.w * QSCALE);
            qf[ks][4] = f2bf(x1.x * QSCALE); qf[ks][5] = f2bf(x1.y * QSCALE);
            qf[ks][6] = f2bf(x1.z * QSCALE); qf[ks][7] = f2bf(x1.w * QSCALE);
        }
    }

    // ---- staging registers (T14: issue early, write late) ----
    float4 kx[4];
    float  vx[16];
    auto issue_loads = [&](int blk) {
        const float4* ksrc = (const float4*)(kh + (size_t)blk * 64 * Dh);
        #pragma unroll
        for (int p = 0; p < 4; ++p) kx[p] = ksrc[tid + p * 256];
        const float* vsrc = vh + ((size_t)blk * 64 + vkq * 16) * Dh + vd;
        #pragma unroll
        for (int i = 0; i < 16; ++i) vx[i] = vsrc[i * Dh];
    };
    auto write_stage = [&](int buf) {
        #pragma unroll
        for (int p = 0; p < 4; ++p) {
            const int fe   = (tid + p * 256) * 4;      // flat element in 64x64 K tile
            const int key  = fe >> 6;
            const int srow = kperm(key);
            const int scol = (fe & 63) ^ ((srow & 7) << 3);
            short4v y;
            y[0] = f2bf(kx[p].x); y[1] = f2bf(kx[p].y);
            y[2] = f2bf(kx[p].z); y[3] = f2bf(kx[p].w);
            *(short4v*)&Klds[buf][srow * 64 + scol] = y;
        }
        frag8 y0, y1;
        #pragma unroll
        for (int i = 0; i < 8; ++i) { y0[i] = f2bf(vx[i]); y1[i] = f2bf(vx[8 + i]); }
        *(frag8*)&Vlds[buf][vd * 64 + ((vkq * 16) ^ vswz)]     = y0;
        *(frag8*)&Vlds[buf][vd * 64 + ((vkq * 16 + 8) ^ vswz)] = y1;
    };

    float m_run = -1e30f, l_run = 0.f;
    f32x4 oacc[4];
    #pragma unroll
    for (int t = 0; t < 4; ++t) oacc[t] = f32x4{0, 0, 0, 0};

    // One KV-block step. Swapped MFMA: S^T = K·Q^T, lane (g,c) owns q-row c,
    // keys {t->r} pre-permuted so exp2 results pack straight into the PV A-frag.
    auto step = [&](int buf) {
        f32x4 s4[4];
        __builtin_amdgcn_s_setprio(1);
        #pragma unroll
        for (int t = 0; t < 4; ++t) {
            f32x4 acc = f32x4{0, 0, 0, 0};
            #pragma unroll
            for (int ks = 0; ks < 2; ++ks) {
                const frag8 kf = *(const frag8*)&Klds[buf][loff[t][ks]];
                acc = __builtin_amdgcn_mfma_f32_16x16x32_bf16(kf, qf[ks], acc, 0, 0, 0);
            }
            s4[t] = acc;
        }
        __builtin_amdgcn_s_setprio(0);

        float pmax = s4[0][0];
        #pragma unroll
        for (int t = 0; t < 4; ++t)
            #pragma unroll
            for (int r = 0; r < 4; ++r) pmax = fmaxf(pmax, s4[t][r]);
        pmax = fmaxf(pmax, __shfl_xor(pmax, 16));
        pmax = fmaxf(pmax, __shfl_xor(pmax, 32));
        if (!__all(pmax <= m_run + DEFER_THR)) {     // T13 defer-max (log2 units)
            const float mn   = fmaxf(m_run, pmax);
            const float corr = __builtin_amdgcn_exp2f(m_run - mn);
            m_run = mn;
            l_run *= corr;
            #pragma unroll
            for (int r = 0; r < 4; ++r) {
                const float cr = __shfl(corr, g * 4 + r);   // O rows are g*4+r
                #pragma unroll
                for (int t = 0; t < 4; ++t) oacc[t][r] *= cr;
            }
        }
        float e[4][4];
        float rs = 0.f;
        #pragma unroll
        for (int t = 0; t < 4; ++t)
            #pragma unroll
            for (int r = 0; r < 4; ++r) {
                e[t][r] = __builtin_amdgcn_exp2f(s4[t][r] - m_run);
                rs += e[t][r];
            }
        rs += __shfl_xor(rs, 16);
        rs += __shfl_xor(rs, 32);
        l_run += rs;

        u32x4 paf[2];
        paf[0] = u32x4{pack2(e[0][0], e[0][1]), pack2(e[0][2], e[0][3]),
                       pack2(e[1][0], e[1][1]), pack2(e[1][2], e[1][3])};
        paf[1] = u32x4{pack2(e[2][0], e[2][1]), pack2(e[2][2], e[2][3]),
                       pack2(e[3][0], e[3][1]), pack2(e[3][2], e[3][3])};
        __builtin_amdgcn_s_setprio(1);
        #pragma unroll
        for (int ks = 0; ks < 2; ++ks) {
            const frag8 pf = __builtin_bit_cast(frag8, paf[ks]);
            #pragma unroll
            for (int t = 0; t < 4; ++t) {
                const frag8 vf = *(const frag8*)&Vlds[buf][loff[t][ks]];
                oacc[t] = __builtin_amdgcn_mfma_f32_16x16x32_bf16(pf, vf, oacc[t], 0, 0, 0);
            }
        }
        __builtin_amdgcn_s_setprio(0);
    };

    // ---- main loop, manually 2x-unrolled so `buf` is a compile-time constant ----
    issue_loads(0);
    write_stage(0);
    int sb = 0;
    while (true) {
        __syncthreads();
        if (sb + 1 < nb) issue_loads(sb + 1);
        step(0);
        if (sb + 1 < nb) write_stage(1);
        if (++sb >= nb) break;

        __syncthreads();
        if (sb + 1 < nb) issue_loads(sb + 1);
        step(1);
        if (sb + 1 < nb) write_stage(0);
        if (++sb >= nb) break;
    }

    // ---- epilogue ----
    const float linv = 1.f / l_run;
    #pragma unroll
    for (int r = 0; r < 4; ++r) {
        const float lr = __shfl(linv, g * 4 + r);
        float* orow = oh + (size_t)(qt * 64 + w * 16 + g * 4 + r) * Dh;
        #pragma unroll
        for (int t = 0; t < 4; ++t) orow[t * 16 + c] = oacc[t][r] * lr;
    }
}

} // namespace

extern "C" void kernel_launch(void* const* d_in, const int* in_sizes, int n_in,
                              void* d_out, int out_size, void* d_ws, size_t ws_size,
                              hipStream_t stream) {
    const float* q = (const float*)d_in[0];
    const float* k = (const float*)d_in[1];
    const float* v = (const float*)d_in[2];
    float* out = (float*)d_out;
    battn_kernel<<<dim3(32 * NT), dim3(256), 0, stream>>>(q, k, v, out);
}